// Round 5
// baseline (243.831 us; speedup 1.0000x reference)
//
// AssociativeMemoryStep — Round 4.
//   cast_x -> weights_all -> fused QKV gemm -> transpose_v -> attn -> O-proj.
// GEMMs rewritten: 128x64 tiles (2x grid => 5-8 blocks/CU), explicit VGPR
// staging (global uint4 loads for k+1 issued BEFORE MFMA on k => latency
// overlapped; gld16-into-same-buffer could not express this), LDS rows padded
// to 80B (frag reads + ds_writes exactly 2 lanes/bank = free, m136), fully
// coalesced monotone global loads. XCD swizzle kept (FETCH 101->22.6 MB in R3).
// Window 512: decay^511 ~ 1.7e-11 relative -> exact truncation.
#include <hip/hip_runtime.h>
#include <math.h>
#include <stdint.h>

#define B_ 4
#define T_ 4096
#define V_ 1024
#define C_ 256
#define WINDOW 512

typedef __bf16 bf16x8 __attribute__((ext_vector_type(8)));
typedef float f32x4 __attribute__((ext_vector_type(4)));
typedef unsigned short us8 __attribute__((ext_vector_type(8)));

__device__ __forceinline__ void gld16(const void* g, void* l) {
  auto gp = reinterpret_cast<const __attribute__((address_space(1))) uint32_t*>(
      reinterpret_cast<uintptr_t>(g));
  auto lp = reinterpret_cast<__attribute__((address_space(3))) uint32_t*>(
      reinterpret_cast<uintptr_t>(l));
  __builtin_amdgcn_global_load_lds(gp, lp, 16, 0, 0);
}

__device__ __forceinline__ unsigned short f2bf(float f) {
  union { float f; unsigned u; } v; v.f = f;
  unsigned r = v.u + 0x7fffu + ((v.u >> 16) & 1u);  // RNE
  return (unsigned short)(r >> 16);
}

// ---------------------------------------------------------------------------
__global__ __launch_bounds__(256) void cast_x_bf16(
    const float* __restrict__ x, unsigned short* __restrict__ xb) {
  const size_t i = ((size_t)blockIdx.x * 256 + threadIdx.x) * 8;
  const float4 a = *(const float4*)(x + i);
  const float4 b = *(const float4*)(x + i + 4);
  us8 o;
  o[0] = f2bf(a.x); o[1] = f2bf(a.y); o[2] = f2bf(a.z); o[3] = f2bf(a.w);
  o[4] = f2bf(b.x); o[5] = f2bf(b.y); o[6] = f2bf(b.z); o[7] = f2bf(b.w);
  *(us8*)(xb + i) = o;
}

// ---------------------------------------------------------------------------
// Weight GEMMs (tiny). z<3: wT[c][v] into concatenated wqkv (q|k|v rows).
// z==3: owb[v][c].
// ---------------------------------------------------------------------------
__global__ __launch_bounds__(256) void weights_all(
    const float* __restrict__ basis, const float* __restrict__ qc,
    const float* __restrict__ kc, const float* __restrict__ vc,
    const float* __restrict__ oc, unsigned short* __restrict__ wqkv,
    unsigned short* __restrict__ owb) {
  const int z = blockIdx.y;
  const float* A; const float* Bm; unsigned short* Cp; int N, bm, bn;
  if (z < 3) {
    A = (z == 0) ? qc : (z == 1) ? kc : vc;
    Bm = basis;
    Cp = wqkv + (size_t)z * 256 * 1024;
    N = 1024; bm = blockIdx.x >> 4; bn = blockIdx.x & 15;
  } else {
    A = basis; Bm = oc; Cp = owb;
    N = 256; bm = blockIdx.x >> 2; bn = blockIdx.x & 3;
  }
  const int m0 = bm * 64, n0 = bn * 64;
  __shared__ float As[16][65];
  __shared__ float Bs[16][65];
  const int tid = threadIdx.x;
  const int tm = tid >> 4, tn = tid & 15;
  float acc[4][4] = {};
  for (int k0 = 0; k0 < 256; k0 += 16) {
#pragma unroll
    for (int r = 0; r < 4; ++r) {
      const int m = (tid >> 4) + 16 * r;
      As[tid & 15][m] = A[(size_t)(m0 + m) * 256 + k0 + (tid & 15)];
      Bs[tid & 15][m] = Bm[(size_t)(n0 + m) * 256 + k0 + (tid & 15)];
    }
    __syncthreads();
#pragma unroll
    for (int k = 0; k < 16; ++k) {
      float a[4], b[4];
#pragma unroll
      for (int i = 0; i < 4; ++i) a[i] = As[k][tm * 4 + i];
#pragma unroll
      for (int j = 0; j < 4; ++j) b[j] = Bs[k][tn * 4 + j];
#pragma unroll
      for (int i = 0; i < 4; ++i)
#pragma unroll
        for (int j = 0; j < 4; ++j) acc[i][j] += a[i] * b[j];
    }
    __syncthreads();
  }
#pragma unroll
  for (int i = 0; i < 4; ++i)
#pragma unroll
    for (int j = 0; j < 4; ++j)
      Cp[(size_t)(m0 + tm * 4 + i) * N + n0 + tn * 4 + j] = f2bf(acc[i][j]);
}

// ---------------------------------------------------------------------------
// bf16 MFMA GEMM, C = alpha * A[M,K] * B[N,K]^T. Tile 128m x 64n, BK=32.
// Explicit VGPR staging pipeline: global loads (k+1) issued before MFMA(k),
// barrier, ds_write(k+1), barrier. LDS rows 80B (64B data + 16B pad):
// frag reads & writes are 2 lanes/bank = conflict-free; global loads fully
// coalesced. Grid 1D = nT * 128 blocks; XCD swizzle: xcd=g&7 owns 16 m-tiles.
// Wave w: quadrant (wm=w&1 of 64m, wn=w>>1 of 32n).
// ---------------------------------------------------------------------------
__global__ __launch_bounds__(256) void gemm_bt_mfma(
    const unsigned short* __restrict__ A, const unsigned short* __restrict__ Bm,
    void* __restrict__ Cp, int Kd, int N, int nT, int outBf16,
    const float* __restrict__ alphaPtr) {
  __shared__ __align__(16) unsigned short As[128 * 40];  // 10 KB
  __shared__ __align__(16) unsigned short Bs[64 * 40];   // 5 KB
  const int tid = threadIdx.x;
  const int g = blockIdx.x;
  const int xcd = g & 7, loc = g >> 3;
  const int n0 = (loc % nT) * 64;
  const int m0 = (xcd * 16 + loc / nT) * 128;
  const int w = tid >> 6, l = tid & 63, q = l >> 4, lm = l & 15;
  const int wm = w & 1, wn = w >> 1;
  const f32x4 zero4 = {0.f, 0.f, 0.f, 0.f};
  f32x4 acc[4][2];
#pragma unroll
  for (int i = 0; i < 4; ++i) { acc[i][0] = zero4; acc[i][1] = zero4; }

  const int arow = tid >> 2, ach = tid & 3;  // 64 rows x 4 chunks per pass
  const char* AgL = (const char*)A + (size_t)(m0 + arow) * Kd * 2 + ach * 16;
  const char* AgH = AgL + (size_t)64 * Kd * 2;
  const char* BgL = (const char*)Bm + (size_t)(n0 + arow) * Kd * 2 + ach * 16;
  unsigned short* wa0 = &As[arow * 40 + ach * 8];
  unsigned short* wa1 = &As[(64 + arow) * 40 + ach * 8];
  unsigned short* wb0 = &Bs[arow * 40 + ach * 8];

  uint4 ra = *(const uint4*)AgL;
  uint4 rb = *(const uint4*)AgH;
  uint4 rc = *(const uint4*)BgL;
  *(uint4*)wa0 = ra; *(uint4*)wa1 = rb; *(uint4*)wb0 = rc;
  __syncthreads();

  for (int k0 = 0;;) {
    const bool more = (k0 + 32) < Kd;
    if (more) {  // prefetch next tile into regs — overlaps MFMA below
      ra = *(const uint4*)(AgL + (size_t)(k0 + 32) * 2);
      rb = *(const uint4*)(AgH + (size_t)(k0 + 32) * 2);
      rc = *(const uint4*)(BgL + (size_t)(k0 + 32) * 2);
    }
    bf16x8 af[4], bf[2];
#pragma unroll
    for (int mt = 0; mt < 4; ++mt)
      af[mt] = *(const bf16x8*)&As[(wm * 64 + mt * 16 + lm) * 40 + q * 8];
#pragma unroll
    for (int nt = 0; nt < 2; ++nt)
      bf[nt] = *(const bf16x8*)&Bs[(wn * 32 + nt * 16 + lm) * 40 + q * 8];
#pragma unroll
    for (int mt = 0; mt < 4; ++mt)
#pragma unroll
      for (int nt = 0; nt < 2; ++nt)
        acc[mt][nt] = __builtin_amdgcn_mfma_f32_16x16x32_bf16(
            af[mt], bf[nt], acc[mt][nt], 0, 0, 0);
    if (!more) break;
    __syncthreads();  // all waves done reading LDS(k)
    *(uint4*)wa0 = ra; *(uint4*)wa1 = rb; *(uint4*)wb0 = rc;
    __syncthreads();  // LDS(k+1) visible
    k0 += 32;
  }

  const float alpha = alphaPtr ? alphaPtr[0] : 1.0f;
#pragma unroll
  for (int mt = 0; mt < 4; ++mt)
#pragma unroll
    for (int nt = 0; nt < 2; ++nt)
#pragma unroll
      for (int r = 0; r < 4; ++r) {
        const int row = m0 + wm * 64 + mt * 16 + q * 4 + r;
        const int col = n0 + wn * 32 + nt * 16 + lm;
        const float vv = acc[mt][nt][r] * alpha;
        if (outBf16)
          ((unsigned short*)Cp)[(size_t)row * N + col] = f2bf(vv);
        else
          ((float*)Cp)[(size_t)row * N + col] = vv;
      }
}

// ---------------------------------------------------------------------------
// Transpose V slice of QKV: QKV[b*T+t][512+c] -> VT[b][c][t]. 64x64 tiles.
// ---------------------------------------------------------------------------
__global__ __launch_bounds__(256) void transpose_v(
    const unsigned short* __restrict__ QKV, unsigned short* __restrict__ VT) {
  __shared__ unsigned short tile[64][65];
  const int tb = blockIdx.x, cb = blockIdx.y, b = blockIdx.z;
  const int tid = threadIdx.x;
#pragma unroll
  for (int r2 = 0; r2 < 2; ++r2) {
    const int idx = r2 * 256 + tid;
    const int row = idx >> 3, p = idx & 7;
    const us8 v = *(const us8*)(QKV +
        ((size_t)(b * T_ + tb * 64 + row)) * 768 + 512 + cb * 64 + p * 8);
#pragma unroll
    for (int j = 0; j < 8; ++j) tile[row][p * 8 + j] = v[j];
  }
  __syncthreads();
#pragma unroll
  for (int r2 = 0; r2 < 2; ++r2) {
    const int idx = r2 * 256 + tid;
    const int c = idx >> 3, p = idx & 7;
    us8 v;
#pragma unroll
    for (int j = 0; j < 8; ++j) v[j] = tile[p * 8 + j][c];
    *(us8*)(VT + ((size_t)b * C_ + cb * 64 + c) * T_ + tb * 64 + p * 8) = v;
  }
}

// ---------------------------------------------------------------------------
// Windowed anti-causal decayed attention (unchanged from R3). t-tile 32,
// s-tile 64, 256 thr, grid 512, XCD-local t-ranges, XOR-swizzled LDS.
// ---------------------------------------------------------------------------
__global__ __launch_bounds__(256) void attn_mfma(
    const unsigned short* __restrict__ QKV, const unsigned short* __restrict__ VT,
    const float* __restrict__ dlp, unsigned short* __restrict__ R) {
  __shared__ __align__(16) unsigned short Kst[16384];  // 32KB
  __shared__ __align__(16) unsigned short Vst[8192];   // 16KB (V half)
  __shared__ __align__(16) unsigned short Ss[32 * 72]; // 4.5KB

  const int g = blockIdx.x;
  const int chunk = (g & 7) * 64 + (g >> 3);
  const int b = chunk >> 7;
  const int t0 = (chunk & 127) << 5;
  const int tid = threadIdx.x;
  const int w = tid >> 6, l = tid & 63, q = l >> 4, lm = l & 15;
  const float dec = 1.f / (1.f + __expf(-dlp[0]));
  const float l2d = log2f(dec);
  const unsigned short* QKVb = QKV + (size_t)b * T_ * 768;
  const int fsw = ((q + (lm >> 1)) & 3) * 16;

  {
    const char* Qg = (const char*)(QKVb + (size_t)t0 * 768);
#pragma unroll
    for (int p = 0; p < 4; ++p) {
      const int o = (p * 256 + tid) * 16;
      const int ch = o >> 11, row = (o >> 6) & 31;
      const int clg = ((((o >> 4) & 3) - (row >> 1)) & 3) * 16;
      gld16(Qg + (size_t)row * 1536 + ch * 64 + clg, (char*)Kst + o);
    }
  }
  __syncthreads();
  bf16x8 qf[2][8];
#pragma unroll
  for (int mt = 0; mt < 2; ++mt)
#pragma unroll
    for (int ch = 0; ch < 8; ++ch)
      qf[mt][ch] = *(const bf16x8*)((const char*)Kst + ch * 2048 +
                                    (mt * 16 + lm) * 64 + fsw);

  const f32x4 zero4 = {0.f, 0.f, 0.f, 0.f};
  f32x4 acc[2][4];
#pragma unroll
  for (int i = 0; i < 2; ++i)
#pragma unroll
    for (int j = 0; j < 4; ++j) acc[i][j] = zero4;

  const int st0 = t0 >> 6;
  const int st1 = min(T_ / 64 - 1, (t0 + 31 + WINDOW) >> 6);
  const char* Kg = (const char*)QKVb + 512;
  const char* Vg = (const char*)(VT + (size_t)b * C_ * T_);

  for (int st = st0; st <= st1; ++st) {
    const int s0 = st << 6;
    __syncthreads();
#pragma unroll
    for (int p = 0; p < 8; ++p) {
      const int o = (p * 256 + tid) * 16;
      const int ch = o >> 12, row = (o >> 6) & 63;
      const int clg = ((((o >> 4) & 3) - (row >> 1)) & 3) * 16;
      gld16(Kg + (size_t)(s0 + row) * 1536 + ch * 64 + clg, (char*)Kst + o);
    }
#pragma unroll
    for (int p = 0; p < 4; ++p) {
      const int o = (p * 256 + tid) * 16;
      const int c = o >> 6;
      const int clg8 = (((o >> 4) & 3) - (c >> 1)) & 3;
      gld16(Vg + ((size_t)c * T_ + s0 + clg8 * 8) * 2, (char*)Vst + o);
    }
    __syncthreads();

    f32x4 sc[2] = {zero4, zero4};
#pragma unroll
    for (int ch = 0; ch < 8; ++ch) {
      const bf16x8 kf = *(const bf16x8*)((const char*)Kst + ch * 4096 +
                                         (w * 16 + lm) * 64 + fsw);
      sc[0] = __builtin_amdgcn_mfma_f32_16x16x32_bf16(qf[0][ch], kf, sc[0], 0, 0, 0);
      sc[1] = __builtin_amdgcn_mfma_f32_16x16x32_bf16(qf[1][ch], kf, sc[1], 0, 0, 0);
    }
    const int sg = s0 + w * 16 + lm;
#pragma unroll
    for (int mt = 0; mt < 2; ++mt)
#pragma unroll
      for (int r = 0; r < 4; ++r) {
        const int trow = t0 + mt * 16 + q * 4 + r;
        const int d = sg - trow;
        const float wgt = (d > 0) ? exp2f(l2d * (float)(d - 1)) : 0.f;
        Ss[(mt * 16 + q * 4 + r) * 72 + w * 16 + lm] = f2bf(sc[mt][r] * wgt);
      }
    __syncthreads();
    bf16x8 sa[2][2];
#pragma unroll
    for (int m2 = 0; m2 < 2; ++m2)
#pragma unroll
      for (int kc2 = 0; kc2 < 2; ++kc2)
        sa[m2][kc2] = *(const bf16x8*)&Ss[(m2 * 16 + lm) * 72 + kc2 * 32 + q * 8];
#pragma unroll
    for (int n2 = 0; n2 < 4; ++n2) {
      const bf16x8 vf = *(const bf16x8*)((const char*)Vst +
                                         (w * 64 + n2 * 16 + lm) * 64 + fsw);
      acc[0][n2] = __builtin_amdgcn_mfma_f32_16x16x32_bf16(sa[0][0], vf, acc[0][n2], 0, 0, 0);
      acc[1][n2] = __builtin_amdgcn_mfma_f32_16x16x32_bf16(sa[1][0], vf, acc[1][n2], 0, 0, 0);
    }
    __syncthreads();
#pragma unroll
    for (int p = 0; p < 4; ++p) {
      const int o = (p * 256 + tid) * 16;
      const int c = o >> 6;
      const int clg8 = (((o >> 4) & 3) - (c >> 1)) & 3;
      gld16(Vg + ((size_t)c * T_ + s0 + 32 + clg8 * 8) * 2, (char*)Vst + o);
    }
    __syncthreads();
#pragma unroll
    for (int n2 = 0; n2 < 4; ++n2) {
      const bf16x8 vf = *(const bf16x8*)((const char*)Vst +
                                         (w * 64 + n2 * 16 + lm) * 64 + fsw);
      acc[0][n2] = __builtin_amdgcn_mfma_f32_16x16x32_bf16(sa[0][1], vf, acc[0][n2], 0, 0, 0);
      acc[1][n2] = __builtin_amdgcn_mfma_f32_16x16x32_bf16(sa[1][1], vf, acc[1][n2], 0, 0, 0);
    }
  }
#pragma unroll
  for (int m2 = 0; m2 < 2; ++m2)
#pragma unroll
    for (int n2 = 0; n2 < 4; ++n2)
#pragma unroll
      for (int r = 0; r < 4; ++r) {
        const int row = t0 + m2 * 16 + q * 4 + r;
        const int col = w * 64 + n2 * 16 + lm;
        R[((size_t)b * T_ + row) * C_ + col] = f2bf(acc[m2][n2][r]);
      }
}

// ---------------------------------------------------------------------------
extern "C" void kernel_launch(void* const* d_in, const int* in_sizes, int n_in,
                              void* d_out, int out_size, void* d_ws,
                              size_t ws_size, hipStream_t stream) {
  const float* x     = (const float*)d_in[0];
  const float* basis = (const float*)d_in[1];
  const float* qc    = (const float*)d_in[2];
  const float* kc    = (const float*)d_in[3];
  const float* vc    = (const float*)d_in[4];
  const float* oc    = (const float*)d_in[5];
  const float* dl    = (const float*)d_in[6];
  const float* osc   = (const float*)d_in[7];
  float* out = (float*)d_out;

  unsigned short* ws = (unsigned short*)d_ws;
  const size_t XSZ = (size_t)B_ * T_ * V_;
  const size_t MSZ = (size_t)B_ * T_ * C_;
  unsigned short* xb   = ws;
  unsigned short* wqkv = xb + XSZ;               // [768,1024]
  unsigned short* owb  = wqkv + 768 * 1024;      // [1024,256]
  unsigned short* QKVb = owb + 1024 * 256;       // [B*T,768] q|k|v
  unsigned short* VTb  = QKVb + (size_t)B_ * T_ * 768;  // [B,256,T]
  unsigned short* Rb   = VTb + MSZ;              // [B*T,256]

  cast_x_bf16<<<dim3(XSZ / (256 * 8)), 256, 0, stream>>>(x, xb);
  weights_all<<<dim3(64, 4), 256, 0, stream>>>(basis, qc, kc, vc, oc, wqkv, owb);
  // fused QKV: [16384,1024] x [768,1024]^T -> bf16 [16384,768]
  gemm_bt_mfma<<<dim3(1536), 256, 0, stream>>>(xb, wqkv, QKVb, V_, 768, 12, 1,
                                               nullptr);
  transpose_v<<<dim3(T_ / 64, C_ / 64, B_), 256, 0, stream>>>(QKVb, VTb);
  attn_mfma<<<dim3((T_ / 32) * B_), 256, 0, stream>>>(QKVb, VTb, dl, Rb);
  // out = out_scale * R @ owb^T : [16384,256] x [1024,256]^T -> fp32
  gemm_bt_mfma<<<dim3(2048), 256, 0, stream>>>(Rb, owb, out, C_, V_, 16, 0, osc);
}